// Round 6
// baseline (279.817 us; speedup 1.0000x reference)
//
#include <hip/hip_runtime.h>
#include <hip/hip_bf16.h>
#include <stdint.h>

#define N_NODES 100000
#define N_EDGES 600000
#define D 128
#define EPS 1e-5f
#define SCAN_BS 512
#define ROW_MASK 0x1FFFF

#define PREP_BLOCKS 321            // (82048+255)/256
#define HIST_BLOCKS 2344           // (N_EDGES+255)/256, 256-thread histogram blocks (K1)
#define XF_BLOCKS   3125           // N_NODES/32, 64-thread 1-wave xform blocks (K3)
#define SC_BLOCKS   2344           // (N_EDGES/4+63)/64, 64-thread x 4-edge scatter blocks (K3)
#define UPD_BLOCKS  3125           // N_NODES/32, 64-thread 1-wave blocks (K4)

typedef __attribute__((ext_vector_type(8))) short short8;
typedef __attribute__((ext_vector_type(16))) float floatx16;

// ---------- helpers ----------

__device__ __forceinline__ uint32_t pack_bf16_rne(float lo, float hi) {
    uint32_t ul = __builtin_bit_cast(uint32_t, lo);
    uint32_t uh = __builtin_bit_cast(uint32_t, hi);
    ul += 0x7fffu + ((ul >> 16) & 1u);
    uh += 0x7fffu + ((uh >> 16) & 1u);
    return (ul >> 16) | (uh & 0xffff0000u);
}

__device__ __forceinline__ unsigned short f32_to_bf16_rne(float f) {
    uint32_t u = __builtin_bit_cast(uint32_t, f);
    u += 0x7fffu + ((u >> 16) & 1u);
    return (unsigned short)(u >> 16);
}

__device__ __forceinline__ float bflo(uint32_t a) { return __builtin_bit_cast(float, a << 16); }
__device__ __forceinline__ float bfhi(uint32_t a) { return __builtin_bit_cast(float, a & 0xffff0000u); }

// global->LDS DMA: no destination VGPRs, depth bounded only by vmcnt.
__device__ __forceinline__ void glds16(const void* g, void* l) {
    __builtin_amdgcn_global_load_lds(
        (const __attribute__((address_space(1))) void*)g,
        (__attribute__((address_space(3))) void*)l, 16, 0, 0);
}
__device__ __forceinline__ void glds4(const void* g, void* l) {
    __builtin_amdgcn_global_load_lds(
        (const __attribute__((address_space(1))) void*)g,
        (__attribute__((address_space(3))) void*)l, 4, 0, 0);
}

// ---------- K1: fused weight preprocessing + destination histogram (+rank) ----------
__global__ void prep_hist(const float* __restrict__ w_m1, const float* __restrict__ w_u1,
                          const float* __restrict__ w_u2, const float* __restrict__ w_m2,
                          const float* __restrict__ b_m2,
                          unsigned short* __restrict__ wm1f, unsigned short* __restrict__ wu1tf,
                          unsigned short* __restrict__ wu2f, unsigned short* __restrict__ wcf,
                          float* __restrict__ vb,
                          const int* __restrict__ col, int* __restrict__ count,
                          int* __restrict__ rank) {
    if (blockIdx.x >= PREP_BLOCKS) {
        int e = (blockIdx.x - PREP_BLOCKS) * 256 + threadIdx.x;
        if (e < N_EDGES) rank[e] = atomicAdd(&count[col[e]], 1);
        return;
    }
    int idx = blockIdx.x * 256 + threadIdx.x;
    if (idx < 32768) {
        int j = idx & 7, lane = (idx >> 3) & 63, t = (idx >> 9) & 3, s = idx >> 11;
        int kk = s * 16 + ((lane >> 5) << 3) + j;
        wm1f[idx] = f32_to_bf16_rne(w_m1[kk * 128 + t * 32 + (lane & 31)]);
    } else if (idx < 49152) {
        int ii = idx - 32768;
        int j = ii & 7, lane = (ii >> 3) & 63, t = (ii >> 9) & 3, s = ii >> 11;
        int kk = s * 16 + ((lane >> 5) << 3) + j;
        wu1tf[ii] = f32_to_bf16_rne(w_u1[kk * 128 + t * 32 + (lane & 31)]);
    } else if (idx < 65536) {
        int ii = idx - 49152;
        int j = ii & 7, lane = (ii >> 3) & 63, t = (ii >> 9) & 3, s = ii >> 11;
        int kk = s * 16 + ((lane >> 5) << 3) + j;
        wu2f[ii] = f32_to_bf16_rne(w_u2[kk * 128 + t * 32 + (lane & 31)]);
    } else if (idx < 81920) {
        int ii = idx - 65536;
        int j = ii & 7, lane = (ii >> 3) & 63, t = (ii >> 9) & 3, s = ii >> 11;
        int kk = s * 16 + ((lane >> 5) << 3) + j;
        int nn = t * 32 + (lane & 31);
        float acc = 0.0f;
        for (int q = 0; q < 128; ++q)
            acc += w_m2[kk * 128 + q] * w_u1[(128 + q) * 128 + nn];
        wcf[ii] = f32_to_bf16_rne(acc);
    } else if (idx < 82048) {
        int nn = idx - 81920;
        float acc = 0.0f;
        for (int q = 0; q < 128; ++q)
            acc += b_m2[q] * w_u1[(128 + q) * 128 + nn];
        vb[nn] = acc;
    }
}

// ---------- K2: single-kernel scan ----------
__global__ void scan_one(const int* __restrict__ count, int* __restrict__ base,
                         int* __restrict__ gcur) {
    __shared__ int tmp[SCAN_BS];
    __shared__ int bbase;
    int g = blockIdx.x * SCAN_BS + threadIdx.x;
    int v = (g < N_NODES) ? count[g] : 0;
    tmp[threadIdx.x] = v;
    __syncthreads();
    int acc = v;
#pragma unroll
    for (int off = 1; off < SCAN_BS; off <<= 1) {
        int add = (threadIdx.x >= off) ? tmp[threadIdx.x - off] : 0;
        __syncthreads();
        acc += add;
        tmp[threadIdx.x] = acc;
        __syncthreads();
    }
    if (threadIdx.x == SCAN_BS - 1) bbase = atomicAdd(gcur, acc);
    __syncthreads();
    if (g < N_NODES) base[g] = bbase + acc - v;
}

// ---------- K3: fused xform (XT|XB+b1 bf16 [node][256]) + atomic-free edge scatter ----------
__launch_bounds__(64, 4)
__global__ void xform_scatter(const float* __restrict__ x, const short8* __restrict__ w1f,
                              const float* __restrict__ b1, unsigned short* __restrict__ xtb,
                              const int* __restrict__ row, const int* __restrict__ col,
                              const int* __restrict__ rank, const int* __restrict__ base,
                              int* __restrict__ srow) {
    if (blockIdx.x >= XF_BLOCKS) {
        int e4 = (((blockIdx.x - XF_BLOCKS) * 64 + threadIdx.x) << 2);
        if (e4 < N_EDGES) {
            int4 r4 = *(const int4*)(row + e4);
            int4 c4 = *(const int4*)(col + e4);
            int4 k4 = *(const int4*)(rank + e4);
            srow[base[c4.x] + k4.x] = r4.x | ((c4.x & 31) << 17);
            srow[base[c4.y] + k4.y] = r4.y | ((c4.y & 31) << 17);
            srow[base[c4.z] + k4.z] = r4.z | ((c4.z & 31) << 17);
            srow[base[c4.w] + k4.w] = r4.w | ((c4.w & 31) << 17);
        }
        return;
    }

    __shared__ __align__(16) short h1[32 * 136];
    const int lane = threadIdx.x;
    const int l31  = lane & 31;
    const int half = lane >> 5;
    short* hl = h1;

    const int nbase = blockIdx.x * 32;          // 3125*32 == N_NODES exactly
    const int n = nbase + l31;
    const float* px = x + (size_t)n * D + half * 8;

    union { short8 v; uint32_t u[4]; } fa[8];
#pragma unroll
    for (int s = 0; s < 8; ++s) {
        const int off = s * 16;
        float4 a0 = *(const float4*)(px + off);
        float4 a1 = *(const float4*)(px + off + 4);
        fa[s].u[0] = pack_bf16_rne(a0.x, a0.y); fa[s].u[1] = pack_bf16_rne(a0.z, a0.w);
        fa[s].u[2] = pack_bf16_rne(a1.x, a1.y); fa[s].u[3] = pack_bf16_rne(a1.z, a1.w);
    }

#pragma unroll
    for (int p = 0; p < 2; ++p) {
        floatx16 acc[4];
#pragma unroll
        for (int t = 0; t < 4; ++t) acc[t] = (floatx16)0.0f;
#pragma unroll
        for (int s = 0; s < 8; ++s) {
#pragma unroll
            for (int t = 0; t < 4; ++t) {
                short8 wf = w1f[((p * 8 + s) * 4 + t) * 64 + lane];
                acc[t] = __builtin_amdgcn_mfma_f32_32x32x16_bf16(fa[s].v, wf, acc[t], 0, 0, 0);
            }
        }
#pragma unroll
        for (int t = 0; t < 4; ++t) {
            float bias = p ? b1[t * 32 + l31] : 0.0f;
#pragma unroll
            for (int r = 0; r < 16; ++r) {
                int m = (r & 3) + 8 * (r >> 2) + 4 * half;
                hl[m * 136 + t * 32 + l31] = (short)f32_to_bf16_rne(acc[t][r] + bias);
            }
        }
#pragma unroll
        for (int it = 0; it < 8; ++it) {
            int off = it * 512 + lane * 8;
            int r2 = off >> 7;
            int c2 = off & 127;
            short8 v = *(const short8*)(hl + r2 * 136 + c2);
            *(short8*)(xtb + (size_t)(nbase + r2) * 256 + p * 128 + c2) = v;
        }
    }
}

// ---------- K4: fused aggregation + update ----------
// Phase A: DMA-staged gather pipeline. XT rows are staged into a 2-slot LDS ring via
// global_load_lds (no dest VGPRs -> regalloc CANNOT collapse the pipeline; depth is
// held by hand-counted vmcnt, never 0 in steady state). pk values are DMA-staged too,
// so ALL phase-A vmem is manually counted. Consume is pure LDS+VALU (XB prestaged).
__launch_bounds__(64, 4)
__global__ void upd_kernel(const float* __restrict__ x, const uint32_t* __restrict__ xtb32,
                           const int* __restrict__ srowpk,
                           const int* __restrict__ base, const int* __restrict__ count,
                           const short8* __restrict__ wu1tf, const short8* __restrict__ wcf,
                           const short8* __restrict__ wu2f,
                           const float* __restrict__ b_u1, const float* __restrict__ vb,
                           const float* __restrict__ b_u2,
                           const float* __restrict__ gamma, const float* __restrict__ beta,
                           float* __restrict__ out) {
    __shared__ __align__(16) short h1[32 * 136];          // accu (phase A) / h + LN (phase B)
    __shared__ __align__(16) uint32_t XBlds[32 * 64];     // 32 XB rows, 8 KB
    __shared__ __align__(16) uint32_t xtring[2048];       // 2 slots x 16 edges x 256 B = 8 KB
    __shared__ __align__(16) uint32_t pkring[128];        // 2 slots x 64 pk
    const int lane = threadIdx.x;
    const int l31  = lane & 31;
    const int half = lane >> 5;
    const int t    = lane & 15;          // lane within quarter
    const int q16  = lane & 48;          // quarter * 16
    short* hl = h1;
    uint32_t* accu = (uint32_t*)hl;      // [32 nodes][64 dwords] bf16-packed

    const int nbase = blockIdx.x * 32;
    const int nc = nbase + l31;

    // per-node CSR info (lane-parallel)
    const int b_l = base[nc];
    const int c_l = count[nc];
    const float dgv = (float)c_l;

    // quarter q owns nodes [8q, 8q+8): contiguous CSR slice
    const int qsrc = q16 >> 1;                           // 8*q
    const int qbeg = __shfl(b_l, qsrc);
    const int qend = __shfl(b_l, qsrc + 7) + __shfl(c_l, qsrc + 7);
    const int rembase = qend - qbeg;

    int ncm = (rembase + 3) >> 2;                        // chunks of 4 edges per quarter
    ncm = max(ncm, __shfl_xor(ncm, 16));
    ncm = max(ncm, __shfl_xor(ncm, 32));                 // wave-uniform max

    // zero accu rows (deg-0 nodes never flushed)
#pragma unroll
    for (int i = 0; i < 8; ++i) {
        uint4 z; z.x = 0; z.y = 0; z.z = 0; z.w = 0;
        *((uint4*)accu + i * 64 + lane) = z;
    }

    // prestage the 32 XB rows into LDS (8 KB, coalesced)
#pragma unroll
    for (int j = 0; j < 8; ++j) {
        int fi = j * 64 + lane;                          // uint4 index 0..511
        int i  = fi >> 4;                                // row
        int k  = fi & 15;                                // uint4 within row
        uint4 v = *(const uint4*)(xtb32 + (size_t)(nbase + i) * 128 + 64 + (k << 2));
        *((uint4*)XBlds + fi) = v;
    }

    // ---- Phase A: DMA ring pipeline (all vmem hand-counted from here) ----
    if (ncm > 0) {
        float sl0 = 0.f, sl1 = 0.f, sl2 = 0.f, sl3 = 0.f;
        float sh0 = 0.f, sh1 = 0.f, sh2 = 0.f, sh3 = 0.f;
        int curnib = -1;
        int pkcur = 0, pknext = 0;

        auto flush = [&]() {
            uint4 o;
            o.x = pack_bf16_rne(sl0, sh0);
            o.y = pack_bf16_rne(sl1, sh1);
            o.z = pack_bf16_rne(sl2, sh2);
            o.w = pack_bf16_rne(sl3, sh3);
            *(uint4*)(accu + (curnib << 6) + (t << 2)) = o;
        };

        // DMA pk chunk c into pkring slot (lane -> edge (q, t&3)); 1 vmem op
        auto stage_pk = [&](int c, int slot) {
            int idx = qbeg + (c << 2) + (t & 3);
            glds4(srowpk + min(idx, N_EDGES - 1), &pkring[slot * 64]);
        };

        // DMA 4 XT rows (one per quarter) x 4 edges of chunk; 4 vmem ops
        auto stage_xt = [&](int pkv, int slot) {
#pragma unroll
            for (int j = 0; j < 4; ++j) {
                int pj = __shfl(pkv, q16 + j);
                const uint32_t* g = xtb32 + (size_t)(pj & ROW_MASK) * 128 + (t << 2);
                glds16(g, &xtring[slot * 1024 + j * 256]);
            }
        };

        // consume chunk c from the ring: pure LDS + VALU, zero vmem
        auto consume = [&](int c) {
            const int rem = rembase - (c << 2);
            const uint32_t* ring = xtring + ((c & 1) << 10);
#pragma unroll
            for (int e = 0; e < 4; ++e) {
                if (e < rem) {
                    int nib = __shfl(pkcur, q16 + e) >> 17;
                    uint4 xt = *(const uint4*)(ring + (e << 8) + (lane << 2));
                    uint4 xb = *(const uint4*)(XBlds + (nib << 6) + (t << 2));
                    float a0 = fmaxf(bflo(xt.x) + bflo(xb.x), 0.f);
                    float b0 = fmaxf(bfhi(xt.x) + bfhi(xb.x), 0.f);
                    float a1 = fmaxf(bflo(xt.y) + bflo(xb.y), 0.f);
                    float b1 = fmaxf(bfhi(xt.y) + bfhi(xb.y), 0.f);
                    float a2 = fmaxf(bflo(xt.z) + bflo(xb.z), 0.f);
                    float b2 = fmaxf(bfhi(xt.z) + bfhi(xb.z), 0.f);
                    float a3 = fmaxf(bflo(xt.w) + bflo(xb.w), 0.f);
                    float b3 = fmaxf(bfhi(xt.w) + bfhi(xb.w), 0.f);
                    if (nib != curnib) {
                        if (curnib >= 0) flush();
                        curnib = nib;
                        sl0 = a0; sh0 = b0; sl1 = a1; sh1 = b1;
                        sl2 = a2; sh2 = b2; sl3 = a3; sh3 = b3;
                    } else {
                        sl0 += a0; sh0 += b0; sl1 += a1; sh1 += b1;
                        sl2 += a2; sh2 += b2; sl3 += a3; sh3 += b3;
                    }
                }
            }
        };

        // drain compiler-tracked loads so DMA counting is exact
        asm volatile("s_waitcnt vmcnt(0)" ::: "memory");

        // prologue: establish invariant {xt[c] x4 (oldest), pk[c+2], xt[c+1] x4}
        stage_pk(0, 0);
        stage_pk(1, 1);
        asm volatile("s_waitcnt vmcnt(1)" ::: "memory");   // pk[0] landed
        pkcur = (int)pkring[lane];
        stage_xt(pkcur, 0);                                 // xt[0]
        asm volatile("s_waitcnt vmcnt(4)" ::: "memory");   // pk[1] landed
        pknext = (int)pkring[64 + lane];
        stage_pk(2, 0);                                     // slot 0 free (pk[0] read)
        stage_xt(pknext, 1);                                // xt[1]

        for (int c = 0; c < ncm; ++c) {
            asm volatile("s_waitcnt vmcnt(5)" ::: "memory"); // xt[c] landed
            __builtin_amdgcn_sched_barrier(0);
            consume(c);
            asm volatile("s_waitcnt vmcnt(4)" ::: "memory"); // pk[c+2] landed
            pkcur = pknext;
            pknext = (int)pkring[(c & 1) * 64 + lane];       // pk[c+2]
            stage_pk(c + 3, (c + 1) & 1);                    // slot held pk[c+1] (read)
            stage_xt(pknext, c & 1);                         // xt[c+2] over consumed slot
        }
        if (curnib >= 0) flush();
    }

    // ---- Phase B: GEMMs + LN (wave-private LDS; per-wave DS ordering suffices) ----
    const float* px = x + (size_t)nc * D + half * 8;

    floatx16 acc[4];
#pragma unroll
    for (int tt = 0; tt < 4; ++tt) acc[tt] = (floatx16)0.0f;

#pragma unroll
    for (int s = 0; s < 16; ++s) {
        union { short8 v; uint32_t u[4]; } fa;
        const short8* bf;
        if (s < 8) {
            const int off = s * 16;
            float4 a0 = *(const float4*)(px + off);
            float4 a1 = *(const float4*)(px + off + 4);
            fa.u[0] = pack_bf16_rne(a0.x, a0.y); fa.u[1] = pack_bf16_rne(a0.z, a0.w);
            fa.u[2] = pack_bf16_rne(a1.x, a1.y); fa.u[3] = pack_bf16_rne(a1.z, a1.w);
            bf = wu1tf + (s * 4) * 64;
        } else {
            fa.v = *(const short8*)((const short*)accu + l31 * 128 + (s - 8) * 16 + half * 8);
            bf = wcf + ((s - 8) * 4) * 64;
        }
#pragma unroll
        for (int tt = 0; tt < 4; ++tt) {
            short8 wf = bf[tt * 64 + lane];
            acc[tt] = __builtin_amdgcn_mfma_f32_32x32x16_bf16(fa.v, wf, acc[tt], 0, 0, 0);
        }
    }

    float bu1[4], vbt[4];
#pragma unroll
    for (int tt = 0; tt < 4; ++tt) {
        bu1[tt] = b_u1[tt * 32 + l31];
        vbt[tt] = vb[tt * 32 + l31];
    }

#pragma unroll
    for (int r = 0; r < 16; ++r) {
        int m = (r & 3) + 8 * (r >> 2) + 4 * half;
        float dg = __shfl(dgv, m, 32);
#pragma unroll
        for (int tt = 0; tt < 4; ++tt) {
            float v = fmaxf(acc[tt][r] + bu1[tt] + dg * vbt[tt], 0.0f);
            hl[m * 136 + tt * 32 + l31] = (short)f32_to_bf16_rne(v);
        }
    }

    floatx16 acc2[4];
#pragma unroll
    for (int tt = 0; tt < 4; ++tt) acc2[tt] = (floatx16)0.0f;

#pragma unroll
    for (int s = 0; s < 8; ++s) {
        short8 af = *(const short8*)(hl + l31 * 136 + s * 16 + half * 8);
#pragma unroll
        for (int tt = 0; tt < 4; ++tt) {
            short8 wf = wu2f[(s * 4 + tt) * 64 + lane];
            acc2[tt] = __builtin_amdgcn_mfma_f32_32x32x16_bf16(af, wf, acc2[tt], 0, 0, 0);
        }
    }

    float g4[4], be4[4], bias2[4];
#pragma unroll
    for (int tt = 0; tt < 4; ++tt) {
        g4[tt]    = gamma[tt * 32 + l31];
        be4[tt]   = beta[tt * 32 + l31];
        bias2[tt] = b_u2[tt * 32 + l31];
    }

    // LN epilogue via LDS (fp32, two 16-row passes reusing hl) -> float4 stores.
    float* hf = (float*)hl;
#pragma unroll
    for (int p = 0; p < 2; ++p) {
#pragma unroll
        for (int rr = 0; rr < 8; ++rr) {
            int r = p * 8 + rr;
            float hv[4];
            float s1 = 0.0f, s2 = 0.0f;
#pragma unroll
            for (int tt = 0; tt < 4; ++tt) {
                hv[tt] = acc2[tt][r] + bias2[tt];
                s1 += hv[tt];
                s2 += hv[tt] * hv[tt];
            }
#pragma unroll
            for (int mask = 1; mask < 32; mask <<= 1) {
                s1 += __shfl_xor(s1, mask);
                s2 += __shfl_xor(s2, mask);
            }
            float mean = s1 * (1.0f / 128.0f);
            float var  = s2 * (1.0f / 128.0f) - mean * mean;
            float rs   = rsqrtf(var + EPS);
            int m = (r & 3) + 8 * (r >> 2) + 4 * half;
            int mrow = m - 16 * p;
#pragma unroll
            for (int tt = 0; tt < 4; ++tt)
                hf[mrow * 132 + tt * 32 + l31] = (hv[tt] - mean) * rs * g4[tt] + be4[tt];
        }
#pragma unroll
        for (int it = 0; it < 8; ++it) {
            int qq = it * 64 + lane;
            int r2 = qq >> 5;
            int c4 = qq & 31;
            int node = nbase + 16 * p + r2;
            float4 v = *(const float4*)(hf + r2 * 132 + c4 * 4);
            float4 xr = *(const float4*)(x + (size_t)node * D + c4 * 4);
            v.x += xr.x; v.y += xr.y; v.z += xr.z; v.w += xr.w;
            *(float4*)(out + (size_t)node * D + c4 * 4) = v;
        }
    }
}

// ---------- launch ----------
extern "C" void kernel_launch(void* const* d_in, const int* in_sizes, int n_in,
                              void* d_out, int out_size, void* d_ws, size_t ws_size,
                              hipStream_t stream) {
    const float* x     = (const float*)d_in[0];
    const int*   edge  = (const int*)d_in[1];
    const float* w_m1  = (const float*)d_in[2];
    const float* b_m1  = (const float*)d_in[3];
    const float* w_m2  = (const float*)d_in[4];
    const float* b_m2  = (const float*)d_in[5];
    const float* w_u1  = (const float*)d_in[6];
    const float* b_u1  = (const float*)d_in[7];
    const float* w_u2  = (const float*)d_in[8];
    const float* b_u2  = (const float*)d_in[9];
    const float* gamma = (const float*)d_in[10];
    const float* beta  = (const float*)d_in[11];
    float* out = (float*)d_out;

    char* ws = (char*)d_ws;
    size_t off = 0;
    auto alloc = [&](size_t bytes) { void* p = ws + off; off = (off + bytes + 15) & ~(size_t)15; return p; };

    unsigned short* xtb   = (unsigned short*)alloc((size_t)N_NODES * 256 * 2);  // XT | XB+b1
    unsigned short* wm1f  = (unsigned short*)alloc(256 * 128 * 2);
    unsigned short* wu1tf = (unsigned short*)alloc(128 * 128 * 2);
    unsigned short* wcf   = (unsigned short*)alloc(128 * 128 * 2);
    unsigned short* wu2f  = (unsigned short*)alloc(128 * 128 * 2);
    float* vb    = (float*)alloc(128 * 4);
    int* count   = (int*)alloc((size_t)N_NODES * 4 + 16);   // + gcur tail
    int* gcur    = count + N_NODES;
    int* base    = (int*)alloc((size_t)N_NODES * 4);
    int* rank    = (int*)alloc((size_t)N_EDGES * 4);
    int* srow    = (int*)alloc((size_t)N_EDGES * 4);

    const int* rowi = edge;            // edge_index[0]
    const int* coli = edge + N_EDGES;  // edge_index[1]
    const int NB = (N_NODES + SCAN_BS - 1) / SCAN_BS;  // 196 blocks

    (void)hipMemsetAsync(count, 0, (size_t)N_NODES * 4 + 16, stream);  // count + gcur

    // K1: all weight prep + destination histogram (+rank harvest)
    prep_hist<<<PREP_BLOCKS + HIST_BLOCKS, 256, 0, stream>>>(
        w_m1, w_u1, w_u2, w_m2, b_m2, wm1f, wu1tf, wu2f, wcf, vb, coli, count, rank);

    // K2: single-kernel scan
    scan_one<<<NB, SCAN_BS, 0, stream>>>(count, base, gcur);

    // K3: xform + atomic-free packed edge scatter fused
    xform_scatter<<<XF_BLOCKS + SC_BLOCKS, 64, 0, stream>>>(
        x, (const short8*)wm1f, b_m1, xtb, rowi, coli, rank, base, srow);

    // K4: fused aggregation + update (DMA-staged gather pipeline)
    upd_kernel<<<UPD_BLOCKS, 64, 0, stream>>>(
        x, (const uint32_t*)xtb, srow, base, count,
        (const short8*)wu1tf, (const short8*)wcf, (const short8*)wu2f,
        b_u1, vb, b_u2, gamma, beta, out);
}

// Round 7
// 257.117 us; speedup vs baseline: 1.0883x; 1.0883x over previous
//
#include <hip/hip_runtime.h>
#include <hip/hip_bf16.h>
#include <stdint.h>

#define N_NODES 100000
#define N_EDGES 600000
#define D 128
#define EPS 1e-5f
#define SCAN_BS 512
#define ROW_MASK 0x1FFFF

#define PREP_BLOCKS 321            // (82048+255)/256
#define HIST_BLOCKS 2344           // (N_EDGES+255)/256, 256-thread histogram blocks (K1)
#define XF_BLOCKS   3125           // N_NODES/32, 64-thread 1-wave xform blocks (K3)
#define SC_BLOCKS   2344           // (N_EDGES/4+63)/64, 64-thread x 4-edge scatter blocks (K3)
#define AGG_BLOCKS  12500          // N_NODES/8, 64-thread 1-wave blocks (K4a)
#define UPD_BLOCKS  3125           // N_NODES/32, 64-thread 1-wave blocks (K4b)

typedef __attribute__((ext_vector_type(8))) short short8;
typedef __attribute__((ext_vector_type(16))) float floatx16;

// ---------- helpers ----------

__device__ __forceinline__ uint32_t pack_bf16_rne(float lo, float hi) {
    uint32_t ul = __builtin_bit_cast(uint32_t, lo);
    uint32_t uh = __builtin_bit_cast(uint32_t, hi);
    ul += 0x7fffu + ((ul >> 16) & 1u);
    uh += 0x7fffu + ((uh >> 16) & 1u);
    return (ul >> 16) | (uh & 0xffff0000u);
}

__device__ __forceinline__ unsigned short f32_to_bf16_rne(float f) {
    uint32_t u = __builtin_bit_cast(uint32_t, f);
    u += 0x7fffu + ((u >> 16) & 1u);
    return (unsigned short)(u >> 16);
}

__device__ __forceinline__ float bflo(uint32_t a) { return __builtin_bit_cast(float, a << 16); }
__device__ __forceinline__ float bfhi(uint32_t a) { return __builtin_bit_cast(float, a & 0xffff0000u); }

// ---------- K1: fused weight preprocessing + destination histogram (+rank) ----------
__global__ void prep_hist(const float* __restrict__ w_m1, const float* __restrict__ w_u1,
                          const float* __restrict__ w_u2, const float* __restrict__ w_m2,
                          const float* __restrict__ b_m2,
                          unsigned short* __restrict__ wm1f, unsigned short* __restrict__ wu1tf,
                          unsigned short* __restrict__ wu2f, unsigned short* __restrict__ wcf,
                          float* __restrict__ vb,
                          const int* __restrict__ col, int* __restrict__ count,
                          int* __restrict__ rank) {
    if (blockIdx.x >= PREP_BLOCKS) {
        int e = (blockIdx.x - PREP_BLOCKS) * 256 + threadIdx.x;
        if (e < N_EDGES) rank[e] = atomicAdd(&count[col[e]], 1);
        return;
    }
    int idx = blockIdx.x * 256 + threadIdx.x;
    if (idx < 32768) {
        int j = idx & 7, lane = (idx >> 3) & 63, t = (idx >> 9) & 3, s = idx >> 11;
        int kk = s * 16 + ((lane >> 5) << 3) + j;
        wm1f[idx] = f32_to_bf16_rne(w_m1[kk * 128 + t * 32 + (lane & 31)]);
    } else if (idx < 49152) {
        int ii = idx - 32768;
        int j = ii & 7, lane = (ii >> 3) & 63, t = (ii >> 9) & 3, s = ii >> 11;
        int kk = s * 16 + ((lane >> 5) << 3) + j;
        wu1tf[ii] = f32_to_bf16_rne(w_u1[kk * 128 + t * 32 + (lane & 31)]);
    } else if (idx < 65536) {
        int ii = idx - 49152;
        int j = ii & 7, lane = (ii >> 3) & 63, t = (ii >> 9) & 3, s = ii >> 11;
        int kk = s * 16 + ((lane >> 5) << 3) + j;
        wu2f[ii] = f32_to_bf16_rne(w_u2[kk * 128 + t * 32 + (lane & 31)]);
    } else if (idx < 81920) {
        int ii = idx - 65536;
        int j = ii & 7, lane = (ii >> 3) & 63, t = (ii >> 9) & 3, s = ii >> 11;
        int kk = s * 16 + ((lane >> 5) << 3) + j;
        int nn = t * 32 + (lane & 31);
        float acc = 0.0f;
        for (int q = 0; q < 128; ++q)
            acc += w_m2[kk * 128 + q] * w_u1[(128 + q) * 128 + nn];
        wcf[ii] = f32_to_bf16_rne(acc);
    } else if (idx < 82048) {
        int nn = idx - 81920;
        float acc = 0.0f;
        for (int q = 0; q < 128; ++q)
            acc += b_m2[q] * w_u1[(128 + q) * 128 + nn];
        vb[nn] = acc;
    }
}

// ---------- K2: single-kernel scan ----------
__global__ void scan_one(const int* __restrict__ count, int* __restrict__ base,
                         int* __restrict__ gcur) {
    __shared__ int tmp[SCAN_BS];
    __shared__ int bbase;
    int g = blockIdx.x * SCAN_BS + threadIdx.x;
    int v = (g < N_NODES) ? count[g] : 0;
    tmp[threadIdx.x] = v;
    __syncthreads();
    int acc = v;
#pragma unroll
    for (int off = 1; off < SCAN_BS; off <<= 1) {
        int add = (threadIdx.x >= off) ? tmp[threadIdx.x - off] : 0;
        __syncthreads();
        acc += add;
        tmp[threadIdx.x] = acc;
        __syncthreads();
    }
    if (threadIdx.x == SCAN_BS - 1) bbase = atomicAdd(gcur, acc);
    __syncthreads();
    if (g < N_NODES) base[g] = bbase + acc - v;
}

// ---------- K3: fused xform (XT|XB+b1 bf16 [node][256]) + atomic-free edge scatter ----------
__launch_bounds__(64, 4)
__global__ void xform_scatter(const float* __restrict__ x, const short8* __restrict__ w1f,
                              const float* __restrict__ b1, unsigned short* __restrict__ xtb,
                              const int* __restrict__ row, const int* __restrict__ col,
                              const int* __restrict__ rank, const int* __restrict__ base,
                              int* __restrict__ srow) {
    if (blockIdx.x >= XF_BLOCKS) {
        int e4 = (((blockIdx.x - XF_BLOCKS) * 64 + threadIdx.x) << 2);
        if (e4 < N_EDGES) {
            int4 r4 = *(const int4*)(row + e4);
            int4 c4 = *(const int4*)(col + e4);
            int4 k4 = *(const int4*)(rank + e4);
            srow[base[c4.x] + k4.x] = r4.x | ((c4.x & 31) << 17);
            srow[base[c4.y] + k4.y] = r4.y | ((c4.y & 31) << 17);
            srow[base[c4.z] + k4.z] = r4.z | ((c4.z & 31) << 17);
            srow[base[c4.w] + k4.w] = r4.w | ((c4.w & 31) << 17);
        }
        return;
    }

    __shared__ __align__(16) short h1[32 * 136];
    const int lane = threadIdx.x;
    const int l31  = lane & 31;
    const int half = lane >> 5;
    short* hl = h1;

    const int nbase = blockIdx.x * 32;          // 3125*32 == N_NODES exactly
    const int n = nbase + l31;
    const float* px = x + (size_t)n * D + half * 8;

    union { short8 v; uint32_t u[4]; } fa[8];
#pragma unroll
    for (int s = 0; s < 8; ++s) {
        const int off = s * 16;
        float4 a0 = *(const float4*)(px + off);
        float4 a1 = *(const float4*)(px + off + 4);
        fa[s].u[0] = pack_bf16_rne(a0.x, a0.y); fa[s].u[1] = pack_bf16_rne(a0.z, a0.w);
        fa[s].u[2] = pack_bf16_rne(a1.x, a1.y); fa[s].u[3] = pack_bf16_rne(a1.z, a1.w);
    }

#pragma unroll
    for (int p = 0; p < 2; ++p) {
        floatx16 acc[4];
#pragma unroll
        for (int t = 0; t < 4; ++t) acc[t] = (floatx16)0.0f;
#pragma unroll
        for (int s = 0; s < 8; ++s) {
#pragma unroll
            for (int t = 0; t < 4; ++t) {
                short8 wf = w1f[((p * 8 + s) * 4 + t) * 64 + lane];
                acc[t] = __builtin_amdgcn_mfma_f32_32x32x16_bf16(fa[s].v, wf, acc[t], 0, 0, 0);
            }
        }
#pragma unroll
        for (int t = 0; t < 4; ++t) {
            float bias = p ? b1[t * 32 + l31] : 0.0f;
#pragma unroll
            for (int r = 0; r < 16; ++r) {
                int m = (r & 3) + 8 * (r >> 2) + 4 * half;
                hl[m * 136 + t * 32 + l31] = (short)f32_to_bf16_rne(acc[t][r] + bias);
            }
        }
#pragma unroll
        for (int it = 0; it < 8; ++it) {
            int off = it * 512 + lane * 8;
            int r2 = off >> 7;
            int c2 = off & 127;
            short8 v = *(const short8*)(hl + r2 * 136 + c2);
            *(short8*)(xtb + (size_t)(nbase + r2) * 256 + p * 128 + c2) = v;
        }
    }
}

// ---------- K4a: aggregation only ----------
// 8 nodes per 1-wave block -> 12500 blocks (~4x the wave count of the fused kernel).
// TLP, not per-wave ILP, hides the gather latency. Each 16-lane quarter owns 2 nodes'
// contiguous CSR slice; 8-deep unconditional gather batches; run-merged bf16 sums in
// a 2KB LDS accumulator; result written IN PLACE over the XB half of xtb (each node's
// XB is only read by its owning wave, from its LDS prestage; XT half untouched).
__launch_bounds__(64, 4)
__global__ void agg_kernel(uint32_t* __restrict__ xtb32, const int* __restrict__ srowpk,
                           const int* __restrict__ base, const int* __restrict__ count) {
    __shared__ __align__(16) uint32_t accu[8 * 64];   // [8 nodes][64 dwords] packed bf16
    __shared__ __align__(16) uint32_t XBl[8 * 64];    // XB rows prestage, 2 KB
    const int lane = threadIdx.x;
    const int t    = lane & 15;          // lane within quarter
    const int q16  = lane & 48;          // quarter * 16

    const int nbase = blockIdx.x * 8;    // 12500*8 == N_NODES exactly

    const int b_l = base[nbase + (lane & 7)];
    const int c_l = count[nbase + (lane & 7)];
    const int qsrc = q16 >> 3;                           // 2*quarter
    const int qbeg = __shfl(b_l, qsrc);
    const int qend = __shfl(b_l, qsrc + 1) + __shfl(c_l, qsrc + 1);
    const int rembase = qend - qbeg;

    int ncm = (rembase + 7) >> 3;                        // chunks of 8 edges per quarter
    ncm = max(ncm, __shfl_xor(ncm, 16));
    ncm = max(ncm, __shfl_xor(ncm, 32));                 // wave-uniform max

    // zero accu (deg-0 nodes never flushed) + prestage XB rows
    {
        uint4 z; z.x = 0; z.y = 0; z.z = 0; z.w = 0;
        *((uint4*)accu + lane) = z;
        *((uint4*)accu + 64 + lane) = z;
    }
#pragma unroll
    for (int it = 0; it < 2; ++it) {
        int fi4 = it * 64 + lane;                        // uint4 index 0..127
        int i = fi4 >> 4, k4 = fi4 & 15;
        *((uint4*)XBl + fi4) = *(const uint4*)(xtb32 + (size_t)(nbase + i) * 128 + 64 + (k4 << 2));
    }

    {
        float sl0 = 0.f, sl1 = 0.f, sl2 = 0.f, sl3 = 0.f;
        float sh0 = 0.f, sh1 = 0.f, sh2 = 0.f, sh3 = 0.f;
        int curnib = -1;

        auto flush = [&]() {
            uint4 o;
            o.x = pack_bf16_rne(sl0, sh0);
            o.y = pack_bf16_rne(sl1, sh1);
            o.z = pack_bf16_rne(sl2, sh2);
            o.w = pack_bf16_rne(sl3, sh3);
            *(uint4*)(accu + (curnib << 6) + (t << 2)) = o;
        };

        for (int c = 0; c < ncm; ++c) {
            int idx = qbeg + (c << 3) + (t & 7);
            int pk = srowpk[min(idx, N_EDGES - 1)];
            const int rem = rembase - (c << 3);          // quarter-uniform remaining

            uint4 xt[8]; int pv[8];
#pragma unroll
            for (int e = 0; e < 8; ++e) {
                int p = __shfl(pk, q16 + e);
                if (e >= rem) p = 0;                     // invalid -> row 0 (L1-hot)
                pv[e] = p;
                xt[e] = *(const uint4*)(xtb32 + (size_t)(p & ROW_MASK) * 128 + (t << 2));
            }
            __builtin_amdgcn_sched_barrier(0);
#pragma unroll
            for (int e = 0; e < 8; ++e) {
                if (e < rem) {
                    int nib = (pv[e] >> 17) & 7;
                    uint4 xb = *(const uint4*)(XBl + (nib << 6) + (t << 2));
                    float a0 = fmaxf(bflo(xt[e].x) + bflo(xb.x), 0.f);
                    float b0 = fmaxf(bfhi(xt[e].x) + bfhi(xb.x), 0.f);
                    float a1 = fmaxf(bflo(xt[e].y) + bflo(xb.y), 0.f);
                    float b1 = fmaxf(bfhi(xt[e].y) + bfhi(xb.y), 0.f);
                    float a2 = fmaxf(bflo(xt[e].z) + bflo(xb.z), 0.f);
                    float b2 = fmaxf(bfhi(xt[e].z) + bfhi(xb.z), 0.f);
                    float a3 = fmaxf(bflo(xt[e].w) + bflo(xb.w), 0.f);
                    float b3 = fmaxf(bfhi(xt[e].w) + bfhi(xb.w), 0.f);
                    if (nib != curnib) {
                        if (curnib >= 0) flush();
                        curnib = nib;
                        sl0 = a0; sh0 = b0; sl1 = a1; sh1 = b1;
                        sl2 = a2; sh2 = b2; sl3 = a3; sh3 = b3;
                    } else {
                        sl0 += a0; sh0 += b0; sl1 += a1; sh1 += b1;
                        sl2 += a2; sh2 += b2; sl3 += a3; sh3 += b3;
                    }
                }
            }
        }
        if (curnib >= 0) flush();
    }

    // write hsum over the XB half of this block's 8 xtb rows (exclusively ours now)
#pragma unroll
    for (int it = 0; it < 2; ++it) {
        int fi4 = it * 64 + lane;
        int i = fi4 >> 4, k4 = fi4 & 15;
        *(uint4*)(xtb32 + (size_t)(nbase + i) * 128 + 64 + (k4 << 2)) = *((uint4*)accu + fi4);
    }
}

// ---------- K4b: update (GEMMs + LN + residual) ----------
__launch_bounds__(64, 4)
__global__ void upd_kernel(const float* __restrict__ x, const uint32_t* __restrict__ xtb32,
                           const int* __restrict__ count,
                           const short8* __restrict__ wu1tf, const short8* __restrict__ wcf,
                           const short8* __restrict__ wu2f,
                           const float* __restrict__ b_u1, const float* __restrict__ vb,
                           const float* __restrict__ b_u2,
                           const float* __restrict__ gamma, const float* __restrict__ beta,
                           float* __restrict__ out) {
    __shared__ __align__(16) short h1[32 * 136];
    const int lane = threadIdx.x;
    const int l31  = lane & 31;
    const int half = lane >> 5;
    short* hl = h1;

    const int nbase = blockIdx.x * 32;
    const int nc = nbase + l31;
    const float dgv = (float)count[nc];

    const float* px = x + (size_t)nc * D + half * 8;
    const short* xtbs = (const short*)xtb32;

    floatx16 acc[4];
#pragma unroll
    for (int tt = 0; tt < 4; ++tt) acc[tt] = (floatx16)0.0f;

#pragma unroll
    for (int s = 0; s < 16; ++s) {
        union { short8 v; uint32_t u[4]; } fa;
        const short8* bf;
        if (s < 8) {
            const int off = s * 16;
            float4 a0 = *(const float4*)(px + off);
            float4 a1 = *(const float4*)(px + off + 4);
            fa.u[0] = pack_bf16_rne(a0.x, a0.y); fa.u[1] = pack_bf16_rne(a0.z, a0.w);
            fa.u[2] = pack_bf16_rne(a1.x, a1.y); fa.u[3] = pack_bf16_rne(a1.z, a1.w);
            bf = wu1tf + (s * 4) * 64;
        } else {
            // hsum lives in the XB half of xtb: [node][256 shorts], offset 128
            fa.v = *(const short8*)(xtbs + (size_t)nc * 256 + 128 + (s - 8) * 16 + half * 8);
            bf = wcf + ((s - 8) * 4) * 64;
        }
#pragma unroll
        for (int tt = 0; tt < 4; ++tt) {
            short8 wf = bf[tt * 64 + lane];
            acc[tt] = __builtin_amdgcn_mfma_f32_32x32x16_bf16(fa.v, wf, acc[tt], 0, 0, 0);
        }
    }

    float bu1[4], vbt[4];
#pragma unroll
    for (int tt = 0; tt < 4; ++tt) {
        bu1[tt] = b_u1[tt * 32 + l31];
        vbt[tt] = vb[tt * 32 + l31];
    }

#pragma unroll
    for (int r = 0; r < 16; ++r) {
        int m = (r & 3) + 8 * (r >> 2) + 4 * half;
        float dg = __shfl(dgv, m, 32);
#pragma unroll
        for (int tt = 0; tt < 4; ++tt) {
            float v = fmaxf(acc[tt][r] + bu1[tt] + dg * vbt[tt], 0.0f);
            hl[m * 136 + tt * 32 + l31] = (short)f32_to_bf16_rne(v);
        }
    }

    floatx16 acc2[4];
#pragma unroll
    for (int tt = 0; tt < 4; ++tt) acc2[tt] = (floatx16)0.0f;

#pragma unroll
    for (int s = 0; s < 8; ++s) {
        short8 af = *(const short8*)(hl + l31 * 136 + s * 16 + half * 8);
#pragma unroll
        for (int tt = 0; tt < 4; ++tt) {
            short8 wf = wu2f[(s * 4 + tt) * 64 + lane];
            acc2[tt] = __builtin_amdgcn_mfma_f32_32x32x16_bf16(af, wf, acc2[tt], 0, 0, 0);
        }
    }

    float g4[4], be4[4], bias2[4];
#pragma unroll
    for (int tt = 0; tt < 4; ++tt) {
        g4[tt]    = gamma[tt * 32 + l31];
        be4[tt]   = beta[tt * 32 + l31];
        bias2[tt] = b_u2[tt * 32 + l31];
    }

    // LN epilogue via LDS (fp32, two 16-row passes reusing hl) -> float4 stores.
    float* hf = (float*)hl;
#pragma unroll
    for (int p = 0; p < 2; ++p) {
#pragma unroll
        for (int rr = 0; rr < 8; ++rr) {
            int r = p * 8 + rr;
            float hv[4];
            float s1 = 0.0f, s2 = 0.0f;
#pragma unroll
            for (int tt = 0; tt < 4; ++tt) {
                hv[tt] = acc2[tt][r] + bias2[tt];
                s1 += hv[tt];
                s2 += hv[tt] * hv[tt];
            }
#pragma unroll
            for (int mask = 1; mask < 32; mask <<= 1) {
                s1 += __shfl_xor(s1, mask);
                s2 += __shfl_xor(s2, mask);
            }
            float mean = s1 * (1.0f / 128.0f);
            float var  = s2 * (1.0f / 128.0f) - mean * mean;
            float rs   = rsqrtf(var + EPS);
            int m = (r & 3) + 8 * (r >> 2) + 4 * half;
            int mrow = m - 16 * p;
#pragma unroll
            for (int tt = 0; tt < 4; ++tt)
                hf[mrow * 132 + tt * 32 + l31] = (hv[tt] - mean) * rs * g4[tt] + be4[tt];
        }
#pragma unroll
        for (int it = 0; it < 8; ++it) {
            int qq = it * 64 + lane;
            int r2 = qq >> 5;
            int c4 = qq & 31;
            int node = nbase + 16 * p + r2;
            float4 v = *(const float4*)(hf + r2 * 132 + c4 * 4);
            float4 xr = *(const float4*)(x + (size_t)node * D + c4 * 4);
            v.x += xr.x; v.y += xr.y; v.z += xr.z; v.w += xr.w;
            *(float4*)(out + (size_t)node * D + c4 * 4) = v;
        }
    }
}

// ---------- launch ----------
extern "C" void kernel_launch(void* const* d_in, const int* in_sizes, int n_in,
                              void* d_out, int out_size, void* d_ws, size_t ws_size,
                              hipStream_t stream) {
    const float* x     = (const float*)d_in[0];
    const int*   edge  = (const int*)d_in[1];
    const float* w_m1  = (const float*)d_in[2];
    const float* b_m1  = (const float*)d_in[3];
    const float* w_m2  = (const float*)d_in[4];
    const float* b_m2  = (const float*)d_in[5];
    const float* w_u1  = (const float*)d_in[6];
    const float* b_u1  = (const float*)d_in[7];
    const float* w_u2  = (const float*)d_in[8];
    const float* b_u2  = (const float*)d_in[9];
    const float* gamma = (const float*)d_in[10];
    const float* beta  = (const float*)d_in[11];
    float* out = (float*)d_out;

    char* ws = (char*)d_ws;
    size_t off = 0;
    auto alloc = [&](size_t bytes) { void* p = ws + off; off = (off + bytes + 15) & ~(size_t)15; return p; };

    unsigned short* xtb   = (unsigned short*)alloc((size_t)N_NODES * 256 * 2);  // XT | XB+b1 (XB half becomes hsum)
    unsigned short* wm1f  = (unsigned short*)alloc(256 * 128 * 2);
    unsigned short* wu1tf = (unsigned short*)alloc(128 * 128 * 2);
    unsigned short* wcf   = (unsigned short*)alloc(128 * 128 * 2);
    unsigned short* wu2f  = (unsigned short*)alloc(128 * 128 * 2);
    float* vb    = (float*)alloc(128 * 4);
    int* count   = (int*)alloc((size_t)N_NODES * 4 + 16);   // + gcur tail
    int* gcur    = count + N_NODES;
    int* base    = (int*)alloc((size_t)N_NODES * 4);
    int* rank    = (int*)alloc((size_t)N_EDGES * 4);
    int* srow    = (int*)alloc((size_t)N_EDGES * 4);

    const int* rowi = edge;            // edge_index[0]
    const int* coli = edge + N_EDGES;  // edge_index[1]
    const int NB = (N_NODES + SCAN_BS - 1) / SCAN_BS;  // 196 blocks

    (void)hipMemsetAsync(count, 0, (size_t)N_NODES * 4 + 16, stream);  // count + gcur

    // K1: all weight prep + destination histogram (+rank harvest)
    prep_hist<<<PREP_BLOCKS + HIST_BLOCKS, 256, 0, stream>>>(
        w_m1, w_u1, w_u2, w_m2, b_m2, wm1f, wu1tf, wu2f, wcf, vb, coli, count, rank);

    // K2: single-kernel scan
    scan_one<<<NB, SCAN_BS, 0, stream>>>(count, base, gcur);

    // K3: xform + atomic-free packed edge scatter fused
    xform_scatter<<<XF_BLOCKS + SC_BLOCKS, 64, 0, stream>>>(
        x, (const short8*)wm1f, b_m1, xtb, rowi, coli, rank, base, srow);

    // K4a: aggregation at 4x wave count (8 nodes/wave); hsum -> XB half of xtb
    agg_kernel<<<AGG_BLOCKS, 64, 0, stream>>>(
        (uint32_t*)xtb, srow, base, count);

    // K4b: update GEMMs + LN + residual (32 nodes/wave)
    upd_kernel<<<UPD_BLOCKS, 64, 0, stream>>>(
        x, (const uint32_t*)xtb, count,
        (const short8*)wu1tf, (const short8*)wcf, (const short8*)wu2f,
        b_u1, vb, b_u2, gamma, beta, out);
}